// Round 5
// baseline (1345.009 us; speedup 1.0000x reference)
//
#include <hip/hip_runtime.h>
#include <hip/hip_bf16.h>
#include <stdint.h>

// BinaryTreeLSTM on MI355X (gfx950) — round 5: persistent kernel + full-K
// register prefetch (AITER-style many-loads-in-flight, no per-step stalls).
//  - 256 blocks x 512 thr; 120KB LDS (persistent B slice) -> 1 block/CU,
//    8 waves/CU. Grid == #CUs, all co-resident (grid barriers safe).
//  - Wave tile = 32 rows x 32 j x 5 gates. ALL 24 A-frags (384 K) loaded into
//    registers up-front (32 x 16B loads in flight), then 24 unrolled k-steps
//    x 5 MFMA consume them in order -> compiler emits descending vmcnt waits.
//  - Leaf level: K=128 (x only), fl/fr gates skipped (children zero).
//  - jt=(blk>>3)&3, stripe=(blk&7)+8*(blk>>5): 4 jt-replicas of a stripe on
//    the same XCD -> shared A rows served from that XCD's L2.
//  - c fp32, h bf16, ping-pong in ws (151 MB, proven size).

#define BATCH 256
#define TDEPTH 10
#define NTOT 1023
#define HDIM 128
#define NCLS 5
#define GDIM 384
#define NKS 24
#define NBLK 256

typedef __bf16 bf16x8 __attribute__((ext_vector_type(8)));
typedef float f32x16 __attribute__((ext_vector_type(16)));

__device__ __forceinline__ float sigmoid_f(float v) { return 1.f / (1.f + __expf(-v)); }
__device__ __forceinline__ float tanh_f(float v) { return 1.f - 2.f / (1.f + __expf(2.f * v)); }

__device__ __forceinline__ void gbar(unsigned* ctr, unsigned target) {
  __syncthreads();
  if (threadIdx.x == 0) {
    __threadfence();
    __hip_atomic_fetch_add(ctr, 1u, __ATOMIC_RELAXED, __HIP_MEMORY_SCOPE_AGENT);
    while (__hip_atomic_load(ctr, __ATOMIC_RELAXED, __HIP_MEMORY_SCOPE_AGENT) < target)
      __builtin_amdgcn_s_sleep(1);
    (void)__hip_atomic_load(ctr, __ATOMIC_ACQUIRE, __HIP_MEMORY_SCOPE_AGENT);
  }
  __syncthreads();
}

// One level's worth of work for one wave. NKSV = 8 (leaf) or 24.
template<int NKSV>
__device__ __forceinline__ void level_body(
    const float* __restrict__ x, const __bf16* Bs,
    const __bf16* __restrict__ h_prev, const float* __restrict__ c_prev,
    __bf16* __restrict__ h_out, float* __restrict__ c_out,
    int d, int wu, int l,
    float g0b, float g1b, float g2b, float g3b, float g4b, int j)
{
  constexpr bool LEAF = (NKSV == 8);
  const int n = 1 << d;
  const int M = BATCH << d;
  const int tiles = M >> 5;
  const int l31 = l & 31;
  const int half8 = (l >> 5) * 8;
  const int rh = (l >> 5) * 4;
  const int n2 = 2 * n;

  for (int t = wu; t < tiles; t += 512) {
    const int m = t * 32 + l31;
    const int b = m >> d;
    const int id = m & (n - 1);
    const size_t xrow = ((size_t)b * NTOT + (n - 1) + id) * HDIM;
    const size_t hrowL = ((size_t)b * n2 + 2 * id) * HDIM;

    // ---- full-K A prefetch: all frags loaded before any MFMA ----
    bf16x8 af[NKSV];
#pragma unroll
    for (int ks = 0; ks < 8; ++ks) {
      const float* s = x + xrow + ks * 16 + half8;
      float4 v0 = *(const float4*)s;
      float4 v1 = *(const float4*)(s + 4);
      bf16x8 w;
      w[0] = (__bf16)v0.x; w[1] = (__bf16)v0.y; w[2] = (__bf16)v0.z; w[3] = (__bf16)v0.w;
      w[4] = (__bf16)v1.x; w[5] = (__bf16)v1.y; w[6] = (__bf16)v1.z; w[7] = (__bf16)v1.w;
      af[ks] = w;
    }
    if constexpr (!LEAF) {
#pragma unroll
      for (int kk = 0; kk < 16; ++kk)
        af[8 + kk] = *(const bf16x8*)(h_prev + hrowL + ((kk >= 8) ? HDIM : 0) + (kk & 7) * 16 + half8);
    }

    f32x16 acc[5];
#pragma unroll
    for (int g = 0; g < 5; ++g)
#pragma unroll
      for (int r = 0; r < 16; ++r) acc[g][r] = 0.f;

#pragma unroll
    for (int ks = 0; ks < NKSV; ++ks) {
#pragma unroll
      for (int g = 0; g < 5; ++g) {
        if (LEAF && (g == 1 || g == 2)) continue;   // children zero: fl/fr unused
        bf16x8 bb = *(const bf16x8*)(Bs + (size_t)(ks * 5 + g) * 512 + l * 8);
        acc[g] = __builtin_amdgcn_mfma_f32_32x32x16_bf16(af[ks], bb, acc[g], 0, 0, 0);
      }
    }

    // ---- epilogue. D layout: col(j)=lane&31, row=(r&3)+8*(r>>2)+4*(lane>>5)
    float clv[16], crv[16];
    if constexpr (!LEAF) {
#pragma unroll
      for (int r = 0; r < 16; ++r) {
        int mm = t * 32 + rh + (r & 3) + 8 * (r >> 2);
        int bb_ = mm >> d;
        int idv = mm & (n - 1);
        size_t cb = ((size_t)bb_ * n2 + 2 * idv) * HDIM + j;
        clv[r] = c_prev[cb];
        crv[r] = c_prev[cb + HDIM];
      }
    }
#pragma unroll
    for (int r = 0; r < 16; ++r) {
      int mm = t * 32 + rh + (r & 3) + 8 * (r >> 2);
      int bb_ = mm >> d;
      int idv = mm & (n - 1);
      float gi = sigmoid_f(acc[0][r] + g0b);
      float go = sigmoid_f(acc[3][r] + g3b);
      float gu = tanh_f(acc[4][r] + g4b);
      float cv = gi * gu;
      if constexpr (!LEAF) {
        float gl = sigmoid_f(acc[1][r] + g1b);
        float gr = sigmoid_f(acc[2][r] + g2b);
        cv += gl * clv[r] + gr * crv[r];
      }
      size_t ob = ((size_t)bb_ * n + idv) * HDIM + j;
      c_out[ob] = cv;
      h_out[ob] = (__bf16)(go * tanh_f(cv));
    }
  }
}

__global__ __launch_bounds__(512, 2) void fused_kernel(
    const float* __restrict__ x,
    const float* __restrict__ W0, const float* __restrict__ W1,
    const float* __restrict__ W2, const float* __restrict__ W3,
    const float* __restrict__ W4,
    const float* __restrict__ bv0, const float* __restrict__ bv1,
    const float* __restrict__ bv2, const float* __restrict__ bv3,
    const float* __restrict__ bv4,
    const float* __restrict__ Wcls, const float* __restrict__ bcls,
    __bf16* hb0, __bf16* hb1, float* cb0, float* cb1,
    unsigned* ctr, float* out)
{
  __shared__ __bf16 Bs[5 * NKS * 512];   // 120 KB: chunk (ks*5+g) = 64 lanes x 16B

  const int tid = threadIdx.x;
  const int jt = (blockIdx.x >> 3) & 3;
  const int stripe = (blockIdx.x & 7) + ((blockIdx.x >> 5) << 3);

  // ---- pack this block's persistent B slice into LDS (once) ----
  for (int e = tid; e < 5 * NKS * 64; e += 512) {
    int c = e >> 6, l = e & 63;
    int ks = c / 5, g = c % 5;
    const float* W = (g == 0) ? W0 : (g == 1) ? W1 : (g == 2) ? W2 : (g == 3) ? W3 : W4;
    const float* s = W + (size_t)(jt * 32 + (l & 31)) * GDIM + ks * 16 + (l >> 5) * 8;
    float4 v0 = *(const float4*)s;
    float4 v1 = *(const float4*)(s + 4);
    bf16x8 w;
    w[0] = (__bf16)v0.x; w[1] = (__bf16)v0.y; w[2] = (__bf16)v0.z; w[3] = (__bf16)v0.w;
    w[4] = (__bf16)v1.x; w[5] = (__bf16)v1.y; w[6] = (__bf16)v1.z; w[7] = (__bf16)v1.w;
    *(bf16x8*)(Bs + (size_t)e * 8) = w;
  }
  __syncthreads();

  const int wave = tid >> 6;
  const int l = tid & 63;
  const int wu = stripe * 8 + wave;          // wave-unit 0..511 per jt
  const int j = jt * 32 + (l & 31);
  const float g0b = bv0[j], g1b = bv1[j], g2b = bv2[j], g3b = bv3[j], g4b = bv4[j];

  unsigned target = 0;

  // leaf level d=9 -> writes hb0/cb0
  level_body<8>(x, Bs, hb1, cb1, hb0, cb0, 9, wu, l, g0b, g1b, g2b, g3b, g4b, j);
  target += NBLK; gbar(ctr, target);

  for (int d = 8; d >= 0; --d) {
    const int p = 9 - d;
    __bf16* h_out = (p & 1) ? hb1 : hb0;
    float*  c_out = (p & 1) ? cb1 : cb0;
    const __bf16* h_prev = (p & 1) ? hb0 : hb1;
    const float*  c_prev = (p & 1) ? cb0 : cb1;
    level_body<24>(x, Bs, h_prev, c_prev, h_out, c_out, d, wu, l,
                   g0b, g1b, g2b, g3b, g4b, j);
    target += NBLK; gbar(ctr, target);
  }

  // ---- classifier: root h in hb1 (p=9) ----
  if (blockIdx.x == 0 && tid < BATCH) {
    const __bf16* hr = hb1 + (size_t)tid * HDIM;
    float s[NCLS];
#pragma unroll
    for (int c = 0; c < NCLS; ++c) s[c] = bcls[c];
    for (int k = 0; k < HDIM; ++k) {
      float hv = (float)hr[k];
#pragma unroll
      for (int c = 0; c < NCLS; ++c) s[c] += hv * Wcls[c * HDIM + k];
    }
#pragma unroll
    for (int c = 0; c < NCLS; ++c) out[tid * NCLS + c] = s[c];
  }
}

extern "C" void kernel_launch(void* const* d_in, const int* in_sizes, int n_in,
                              void* d_out, int out_size, void* d_ws, size_t ws_size,
                              hipStream_t stream) {
  const float* x  = (const float*)d_in[0];
  const float* W[5]  = {(const float*)d_in[1], (const float*)d_in[3], (const float*)d_in[5],
                        (const float*)d_in[7], (const float*)d_in[9]};
  const float* bv[5] = {(const float*)d_in[2], (const float*)d_in[4], (const float*)d_in[6],
                        (const float*)d_in[8], (const float*)d_in[10]};
  const float* Wcls = (const float*)d_in[11];
  const float* bcls = (const float*)d_in[12];

  uint8_t* ws = (uint8_t*)d_ws;
  __bf16* hb0 = (__bf16*)ws;                       // 33.5 MB (levels 9,7,5,..)
  __bf16* hb1 = (__bf16*)(ws + 33554432);          // 16.8 MB (levels 8,6,..,0)
  float*  cb0 = (float*)(ws + 50331648);           // 67 MB
  float*  cb1 = (float*)(ws + 117440512);          // 33.5 MB
  unsigned* ctr = (unsigned*)(ws + 150994944);     // 64 B barrier counter

  hipMemsetAsync((void*)ctr, 0, 64, stream);
  fused_kernel<<<NBLK, 512, 0, stream>>>(
      x, W[0], W[1], W[2], W[3], W[4],
      bv[0], bv[1], bv[2], bv[3], bv[4],
      Wcls, bcls, hb0, hb1, cb0, cb1, ctr, (float*)d_out);
}